// Round 1
// baseline (313.721 us; speedup 1.0000x reference)
//
#include <hip/hip_runtime.h>
#include <stdint.h>

// Disable FP contraction file-wide: the d2 <= R2 inclusion test is a discrete
// decision that must match the reference's fp32 mul+add rounding (XLA/numpy do
// not fuse into fma across ops).
#pragma clang fp contract(off)

#define S 256
#define NPTS 100000
#define BATCH 4
#define CCH 64
#define K 8

static constexpr float R2 = 0.01171875f * 0.01171875f;  // (1.5/256*2)^2, exact
static constexpr unsigned long long SENT = 0xFFFFFFFFFFFFFFFFULL;

// ---------------------------------------------------------------------------
// Kernel 1: scatter points into per-pixel sorted top-K key lists.
// key = (z_bits << 32) | point_idx  -- ascending (z, idx) == reference lexsort
// rank order within a pixel. Concurrent insertion via atomicMin cascade:
// slot array converges to the K smallest keys, sorted, independent of
// interleaving (multiset-preservation argument per slot).
// ---------------------------------------------------------------------------
__global__ void scatter_kernel(const float* __restrict__ pts,
                               unsigned long long* __restrict__ keys) {
    int gid = blockIdx.x * blockDim.x + threadIdx.x;
    if (gid >= BATCH * NPTS) return;
    int b = gid / NPTS;
    int n = gid - b * NPTS;

    const float* p = pts + (size_t)gid * 3;
    float x = -p[0];                 // reference flips x,y signs
    float y = -p[1];
    float z = p[2];
    if (!(z >= 0.0f)) return;

    float px = (1.0f - x) * 128.0f - 0.5f;   // (1-x)*(S/2) - 0.5
    float py = (1.0f - y) * 128.0f - 0.5f;
    int cj0 = (int)floorf(px);
    int ci0 = (int)floorf(py);
    // window rows ci0-1..ci0+2 must intersect [0,S)
    if (ci0 < -2 || ci0 > S || cj0 < -2 || cj0 > S) return;

    unsigned long long zkey =
        ((unsigned long long)__float_as_uint(z) << 32) | (unsigned int)n;
    unsigned long long* kb = keys + (size_t)b * S * S * K;

    for (int a = 0; a < 4; ++a) {
        int ci = ci0 - 1 + a;
        if (ci < 0 || ci >= S) continue;
        float cy = 1.0f - 2.0f * ((float)ci + 0.5f) / 256.0f;
        float dy = cy - y;
        float dy2 = dy * dy;
        for (int d = 0; d < 4; ++d) {
            int cj = cj0 - 1 + d;
            if (cj < 0 || cj >= S) continue;
            float cx = 1.0f - 2.0f * ((float)cj + 0.5f) / 256.0f;
            float dx = cx - x;
            float dx2 = dx * dx;
            float d2 = dy2 + dx2;
            if (d2 <= R2) {
                unsigned long long key = zkey;
                unsigned long long* slot = kb + (size_t)(ci * S + cj) * K;
                for (int s = 0; s < K; ++s) {
                    if (key == SENT) break;
                    unsigned long long old = atomicMin(&slot[s], key);
                    key = old > key ? old : key;   // displaced value continues
                }
            }
        }
    }
}

// ---------------------------------------------------------------------------
// Kernel 2: per-pixel alpha compositing + feature gather + transposed store.
// Block = 256 threads handles (batch b, row h, 64-pixel segment).
//   Phase 1: decode keys -> alpha (d2 recomputed from point coords), LDS.
//   Phase 2: wave i (64 lanes = 64 channels) accumulates 16 pixels;
//            feature row reads are coalesced 256B per wave.
//   Phase 3: lane c stores 16 contiguous w-floats = one full 64B line.
// ---------------------------------------------------------------------------
__global__ __launch_bounds__(256) void blend_kernel(
        const float* __restrict__ pts,
        const float* __restrict__ feat,
        const unsigned long long* __restrict__ keys,
        float* __restrict__ out) {
    int seg = blockIdx.x;   // 0..3  (w segment)
    int h   = blockIdx.y;   // 0..255
    int b   = blockIdx.z;   // 0..3
    int tid = threadIdx.x;
    int w0  = seg * 64;

    __shared__ float s_alpha[64][K];
    __shared__ float s_wgt[64][K];
    __shared__ int   s_idx[64][K];

    const unsigned long long* kb =
        keys + ((size_t)b * S * S + (size_t)h * S + w0) * K;
    const float* pb = pts + (size_t)b * NPTS * 3;

    // Phase 1: 512 entries, 2 per thread
    for (int e = tid; e < 64 * K; e += 256) {
        int p = e >> 3;
        int k = e & 7;
        unsigned long long key = kb[(size_t)p * K + k];
        float alpha = 0.0f;
        int idx = -1;
        if (key != SENT) {
            idx = (int)(unsigned int)(key & 0xFFFFFFFFULL);
            float x = -pb[(size_t)idx * 3 + 0];
            float y = -pb[(size_t)idx * 3 + 1];
            int w = w0 + p;
            float cy = 1.0f - 2.0f * ((float)h + 0.5f) / 256.0f;
            float cx = 1.0f - 2.0f * ((float)w + 0.5f) / 256.0f;
            float dy = cy - y;
            float dx = cx - x;
            float d2 = dy * dy + dx * dx;
            float dist = d2 / R2;
            dist = fminf(fmaxf(dist, 0.001f), 1.0f);
            alpha = 1.0f - sqrtf(dist);     // gamma = 1 -> **0.5
        }
        s_alpha[p][k] = alpha;
        s_idx[p][k] = idx;
    }
    __syncthreads();

    // exclusive cumprod of (1 - alpha) -> weights
    if (tid < 64) {
        float t = 1.0f;
        for (int k = 0; k < K; ++k) {
            float a = s_alpha[tid][k];
            s_wgt[tid][k] = a * t;
            t *= (1.0f - a);
        }
    }
    __syncthreads();

    // Phase 2: accumulate
    int wave = tid >> 6;    // 0..3
    int lane = tid & 63;    // channel
    float acc[16];
#pragma unroll
    for (int i = 0; i < 16; ++i) acc[i] = 0.0f;
    const float* fb = feat + (size_t)b * NPTS * CCH;
    int pbase = wave * 16;
    for (int pl = 0; pl < 16; ++pl) {
        int p = pbase + pl;
        for (int k = 0; k < K; ++k) {
            int idx = s_idx[p][k];           // broadcast (same addr all lanes)
            if (idx < 0) break;              // sentinel tail only -> uniform
            acc[pl] += s_wgt[p][k] * fb[(size_t)idx * CCH + lane];
        }
    }

    // Phase 3: transposed store, one 64B line per lane (4x float4)
    size_t obase = (((size_t)b * CCH + lane) * S + h) * S + (size_t)(w0 + pbase);
    float4* o4 = (float4*)(out + obase);
#pragma unroll
    for (int q = 0; q < 4; ++q) {
        o4[q] = make_float4(acc[4 * q + 0], acc[4 * q + 1],
                            acc[4 * q + 2], acc[4 * q + 3]);
    }
}

extern "C" void kernel_launch(void* const* d_in, const int* in_sizes, int n_in,
                              void* d_out, int out_size, void* d_ws, size_t ws_size,
                              hipStream_t stream) {
    const float* pts  = (const float*)d_in[0];
    const float* feat = (const float*)d_in[1];
    float* out = (float*)d_out;

    unsigned long long* keys = (unsigned long long*)d_ws;
    size_t key_bytes = (size_t)BATCH * S * S * K * sizeof(unsigned long long);
    hipMemsetAsync(keys, 0xFF, key_bytes, stream);   // SENT = all-ones

    int total = BATCH * NPTS;
    scatter_kernel<<<(total + 255) / 256, 256, 0, stream>>>(pts, keys);

    dim3 grid(S / 64, S, BATCH);
    blend_kernel<<<grid, 256, 0, stream>>>(pts, feat, keys, out);
}

// Round 2
// 277.745 us; speedup vs baseline: 1.1295x; 1.1295x over previous
//
#include <hip/hip_runtime.h>
#include <stdint.h>

// Disable FP contraction file-wide: the d2 <= R2 inclusion test is a discrete
// decision that must match the reference's fp32 mul+add rounding (XLA/numpy do
// not fuse into fma across ops).
#pragma clang fp contract(off)

#define S 256
#define NPTS 100000
#define BATCH 4
#define CCH 64
#define K 8

static constexpr float R2 = 0.01171875f * 0.01171875f;  // (1.5/256*2)^2, exact
static constexpr unsigned long long SENT = 0xFFFFFFFFFFFFFFFFULL;

// ---------------------------------------------------------------------------
// Kernel 1: scatter points into per-pixel sorted top-K key lists.
// key = (z_bits << 32) | point_idx  -- ascending (z, idx) == reference lexsort
// rank order within a pixel. Concurrent insertion via atomicMin cascade:
// slot array converges to the K smallest keys, sorted, independent of
// interleaving.
// ---------------------------------------------------------------------------
__global__ void scatter_kernel(const float* __restrict__ pts,
                               unsigned long long* __restrict__ keys) {
    int gid = blockIdx.x * blockDim.x + threadIdx.x;
    if (gid >= BATCH * NPTS) return;
    int b = gid / NPTS;
    int n = gid - b * NPTS;

    const float* p = pts + (size_t)gid * 3;
    float x = -p[0];                 // reference flips x,y signs
    float y = -p[1];
    float z = p[2];
    if (!(z >= 0.0f)) return;

    float px = (1.0f - x) * 128.0f - 0.5f;   // (1-x)*(S/2) - 0.5
    float py = (1.0f - y) * 128.0f - 0.5f;
    int cj0 = (int)floorf(px);
    int ci0 = (int)floorf(py);
    if (ci0 < -2 || ci0 > S || cj0 < -2 || cj0 > S) return;

    unsigned long long zkey =
        ((unsigned long long)__float_as_uint(z) << 32) | (unsigned int)n;
    unsigned long long* kb = keys + (size_t)b * S * S * K;

    for (int a = 0; a < 4; ++a) {
        int ci = ci0 - 1 + a;
        if (ci < 0 || ci >= S) continue;
        float cy = 1.0f - 2.0f * ((float)ci + 0.5f) / 256.0f;
        float dy = cy - y;
        float dy2 = dy * dy;
        for (int d = 0; d < 4; ++d) {
            int cj = cj0 - 1 + d;
            if (cj < 0 || cj >= S) continue;
            float cx = 1.0f - 2.0f * ((float)cj + 0.5f) / 256.0f;
            float dx = cx - x;
            float dx2 = dx * dx;
            float d2 = dy2 + dx2;
            if (d2 <= R2) {
                unsigned long long key = zkey;
                unsigned long long* slot = kb + (size_t)(ci * S + cj) * K;
                for (int s = 0; s < K; ++s) {
                    if (key == SENT) break;
                    unsigned long long old = atomicMin(&slot[s], key);
                    key = old > key ? old : key;   // displaced value continues
                }
            }
        }
    }
}

// ---------------------------------------------------------------------------
// Kernel 2: per-pixel alpha compositing + feature gather + transposed store.
// Block = 256 threads handles (batch b, row h, 64-pixel segment).
//   Phase 1: decode keys -> alpha (d2 recomputed from point coords), LDS.
//   Phase 2: k-major loop (uniform trip = wave max count): 16 independent
//            gathers in flight per iteration; invalid slots gather clamped
//            idx 0 with weight 0 (matches reference f[clip(i,0)] * 0).
//   Phase 3: lane c stores 16 contiguous w-floats (4x float4 = 64B line).
// LDS arrays padded to K+1=9 to break the 16-way cumprod bank conflict.
// ---------------------------------------------------------------------------
__global__ __launch_bounds__(256) void blend_kernel(
        const float* __restrict__ pts,
        const float* __restrict__ feat,
        const unsigned long long* __restrict__ keys,
        float* __restrict__ out) {
    int seg = blockIdx.x;   // 0..3  (w segment)
    int h   = blockIdx.y;   // 0..255
    int b   = blockIdx.z;   // 0..3
    int tid = threadIdx.x;
    int w0  = seg * 64;

    __shared__ float s_alpha[64][K + 1];
    __shared__ float s_wgt[64][K + 1];
    __shared__ int   s_idx[64][K + 1];
    __shared__ int   s_cnt[64];

    const unsigned long long* kb =
        keys + ((size_t)b * S * S + (size_t)h * S + w0) * K;
    const float* pb = pts + (size_t)b * NPTS * 3;

    // Phase 1: 512 entries, 2 per thread
    for (int e = tid; e < 64 * K; e += 256) {
        int p = e >> 3;
        int k = e & 7;
        unsigned long long key = kb[(size_t)p * K + k];
        float alpha = 0.0f;
        int idx = -1;
        if (key != SENT) {
            idx = (int)(unsigned int)(key & 0xFFFFFFFFULL);
            float x = -pb[(size_t)idx * 3 + 0];
            float y = -pb[(size_t)idx * 3 + 1];
            int w = w0 + p;
            float cy = 1.0f - 2.0f * ((float)h + 0.5f) / 256.0f;
            float cx = 1.0f - 2.0f * ((float)w + 0.5f) / 256.0f;
            float dy = cy - y;
            float dx = cx - x;
            float d2 = dy * dy + dx * dx;
            float dist = d2 / R2;
            dist = fminf(fmaxf(dist, 0.001f), 1.0f);
            alpha = 1.0f - sqrtf(dist);     // gamma = 1 -> **0.5
        }
        s_alpha[p][k] = alpha;
        s_idx[p][k] = idx;
    }
    __syncthreads();

    // exclusive cumprod of (1 - alpha) -> weights; count valid (contiguous
    // from slot 0 by construction); clamp idx for safe gather.
    if (tid < 64) {
        float t = 1.0f;
        int cnt = 0;
        for (int k = 0; k < K; ++k) {
            int raw = s_idx[tid][k];
            float a = s_alpha[tid][k];      // already 0 for invalid
            s_wgt[tid][k] = a * t;
            t *= (1.0f - a);
            if (raw >= 0) cnt = k + 1;
            s_idx[tid][k] = raw < 0 ? 0 : raw;
        }
        s_cnt[tid] = cnt;
    }
    __syncthreads();

    // Phase 2: k-major accumulate, 16 independent gathers in flight
    int wave = tid >> 6;    // 0..3
    int lane = tid & 63;    // channel
    int pbase = wave * 16;

    int kmax = 0;
#pragma unroll
    for (int i = 0; i < 16; ++i) {
        int c = s_cnt[pbase + i];
        kmax = c > kmax ? c : kmax;
    }

    float acc[16];
#pragma unroll
    for (int i = 0; i < 16; ++i) acc[i] = 0.0f;

    const float* fbl = feat + (size_t)b * NPTS * CCH + lane;
    for (int k = 0; k < kmax; ++k) {
        float v[16];
#pragma unroll
        for (int i = 0; i < 16; ++i) {
            int idx = s_idx[pbase + i][k];          // wave-uniform broadcast
            v[i] = fbl[(size_t)idx << 6];
        }
#pragma unroll
        for (int i = 0; i < 16; ++i) {
            acc[i] += s_wgt[pbase + i][k] * v[i];
        }
    }

    // Phase 3: transposed store, one 64B line per lane (4x float4)
    size_t obase = (((size_t)b * CCH + lane) * S + h) * S + (size_t)(w0 + pbase);
    float4* o4 = (float4*)(out + obase);
#pragma unroll
    for (int q = 0; q < 4; ++q) {
        o4[q] = make_float4(acc[4 * q + 0], acc[4 * q + 1],
                            acc[4 * q + 2], acc[4 * q + 3]);
    }
}

extern "C" void kernel_launch(void* const* d_in, const int* in_sizes, int n_in,
                              void* d_out, int out_size, void* d_ws, size_t ws_size,
                              hipStream_t stream) {
    const float* pts  = (const float*)d_in[0];
    const float* feat = (const float*)d_in[1];
    float* out = (float*)d_out;

    unsigned long long* keys = (unsigned long long*)d_ws;
    size_t key_bytes = (size_t)BATCH * S * S * K * sizeof(unsigned long long);
    hipMemsetAsync(keys, 0xFF, key_bytes, stream);   // SENT = all-ones

    int total = BATCH * NPTS;
    scatter_kernel<<<(total + 255) / 256, 256, 0, stream>>>(pts, keys);

    dim3 grid(S / 64, S, BATCH);
    blend_kernel<<<grid, 256, 0, stream>>>(pts, feat, keys, out);
}

// Round 3
// 274.157 us; speedup vs baseline: 1.1443x; 1.0131x over previous
//
#include <hip/hip_runtime.h>
#include <stdint.h>

// Disable FP contraction file-wide: the d2 <= R2 inclusion test is a discrete
// decision that must match the reference's fp32 mul+add rounding (XLA/numpy do
// not fuse into fma across ops).
#pragma clang fp contract(off)

#define S 256
#define NPTS 100000
#define BATCH 4
#define CCH 64
#define K 8

static constexpr float R2 = 0.01171875f * 0.01171875f;  // (1.5/256*2)^2, exact
static constexpr unsigned long long SENT = 0xFFFFFFFFFFFFFFFFULL;

// ---------------------------------------------------------------------------
// Kernel 1: scatter candidates into per-pixel sorted top-K key lists.
// ONE THREAD PER (point, cell-of-4x4-window): 16 consecutive threads share a
// point (loads broadcast from L1), each owns at most one atomicMin cascade
// -> dependent atomic chain length ~2-3 instead of ~20-50, and 16x more
// independent chains for latency hiding.
//
// key = (z_bits << 32) | point_idx  -- ascending (z, idx) == reference
// lexsort rank. Slots are monotone non-increasing under atomicMin, so:
//  * the slot array converges to the K smallest inserted keys, sorted,
//    independent of interleaving;
//  * prefilter: if a plain load of slot[K-1] < key, key cannot be in the
//    final top-K (monotonicity), and omitting a non-top-K key does not
//    change the converged state -> safe skip.
// ---------------------------------------------------------------------------
__global__ __launch_bounds__(256) void scatter_kernel(
        const float* __restrict__ pts,
        unsigned long long* __restrict__ keys) {
    int gid = blockIdx.x * blockDim.x + threadIdx.x;
    if (gid >= BATCH * NPTS * 16) return;
    int cell = gid & 15;
    int pid  = gid >> 4;
    int b = pid / NPTS;
    int n = pid - b * NPTS;

    const float* p = pts + (size_t)pid * 3;
    float x = -p[0];                 // reference flips x,y signs
    float y = -p[1];
    float z = p[2];
    if (!(z >= 0.0f)) return;

    float px = (1.0f - x) * 128.0f - 0.5f;   // (1-x)*(S/2) - 0.5
    float py = (1.0f - y) * 128.0f - 0.5f;
    int cj0 = (int)floorf(px);
    int ci0 = (int)floorf(py);

    int ci = ci0 - 1 + (cell >> 2);
    int cj = cj0 - 1 + (cell & 3);
    if (ci < 0 || ci >= S || cj < 0 || cj >= S) return;

    float cy = 1.0f - 2.0f * ((float)ci + 0.5f) / 256.0f;
    float cx = 1.0f - 2.0f * ((float)cj + 0.5f) / 256.0f;
    float dy = cy - y;
    float dx = cx - x;
    float d2 = dy * dy + dx * dx;
    if (!(d2 <= R2)) return;

    unsigned long long key =
        ((unsigned long long)__float_as_uint(z) << 32) | (unsigned int)n;
    unsigned long long* slot =
        keys + ((size_t)b * S * S + (size_t)(ci * S + cj)) * K;

    // prefilter: monotone slots => stale read is conservative (larger)
    if (slot[K - 1] < key) return;

    for (int s = 0; s < K; ++s) {
        if (key == SENT) break;
        unsigned long long old = atomicMin(&slot[s], key);
        key = old > key ? old : key;   // displaced value continues down
    }
}

// ---------------------------------------------------------------------------
// Kernel 2: per-pixel alpha compositing + feature gather + transposed store.
// Block = 256 threads handles (batch b, row h, 64-pixel segment).
//   Phase 1: decode keys -> alpha (d2 recomputed from point coords), LDS.
//   Phase 2: k-major loop (uniform trip = wave max count): 16 independent
//            gathers in flight per iteration; invalid slots gather clamped
//            idx 0 with weight 0 (matches reference f[clip(i,0)] * 0).
//   Phase 3: lane c stores 16 contiguous w-floats (4x float4 = 64B line).
// LDS arrays padded to K+1=9 to break the 16-way cumprod bank conflict.
// ---------------------------------------------------------------------------
__global__ __launch_bounds__(256) void blend_kernel(
        const float* __restrict__ pts,
        const float* __restrict__ feat,
        const unsigned long long* __restrict__ keys,
        float* __restrict__ out) {
    int seg = blockIdx.x;   // 0..3  (w segment)
    int h   = blockIdx.y;   // 0..255
    int b   = blockIdx.z;   // 0..3
    int tid = threadIdx.x;
    int w0  = seg * 64;

    __shared__ float s_alpha[64][K + 1];
    __shared__ float s_wgt[64][K + 1];
    __shared__ int   s_idx[64][K + 1];
    __shared__ int   s_cnt[64];

    const unsigned long long* kb =
        keys + ((size_t)b * S * S + (size_t)h * S + w0) * K;
    const float* pb = pts + (size_t)b * NPTS * 3;

    // Phase 1: 512 entries, 2 per thread
    for (int e = tid; e < 64 * K; e += 256) {
        int p = e >> 3;
        int k = e & 7;
        unsigned long long key = kb[(size_t)p * K + k];
        float alpha = 0.0f;
        int idx = -1;
        if (key != SENT) {
            idx = (int)(unsigned int)(key & 0xFFFFFFFFULL);
            float x = -pb[(size_t)idx * 3 + 0];
            float y = -pb[(size_t)idx * 3 + 1];
            int w = w0 + p;
            float cy = 1.0f - 2.0f * ((float)h + 0.5f) / 256.0f;
            float cx = 1.0f - 2.0f * ((float)w + 0.5f) / 256.0f;
            float dy = cy - y;
            float dx = cx - x;
            float d2 = dy * dy + dx * dx;
            float dist = d2 / R2;
            dist = fminf(fmaxf(dist, 0.001f), 1.0f);
            alpha = 1.0f - sqrtf(dist);     // gamma = 1 -> **0.5
        }
        s_alpha[p][k] = alpha;
        s_idx[p][k] = idx;
    }
    __syncthreads();

    // exclusive cumprod of (1 - alpha) -> weights; count valid (contiguous
    // from slot 0 by construction); clamp idx for safe gather.
    if (tid < 64) {
        float t = 1.0f;
        int cnt = 0;
        for (int k = 0; k < K; ++k) {
            int raw = s_idx[tid][k];
            float a = s_alpha[tid][k];      // already 0 for invalid
            s_wgt[tid][k] = a * t;
            t *= (1.0f - a);
            if (raw >= 0) cnt = k + 1;
            s_idx[tid][k] = raw < 0 ? 0 : raw;
        }
        s_cnt[tid] = cnt;
    }
    __syncthreads();

    // Phase 2: k-major accumulate, 16 independent gathers in flight
    int wave = tid >> 6;    // 0..3
    int lane = tid & 63;    // channel
    int pbase = wave * 16;

    int kmax = 0;
#pragma unroll
    for (int i = 0; i < 16; ++i) {
        int c = s_cnt[pbase + i];
        kmax = c > kmax ? c : kmax;
    }

    float acc[16];
#pragma unroll
    for (int i = 0; i < 16; ++i) acc[i] = 0.0f;

    const float* fbl = feat + (size_t)b * NPTS * CCH + lane;
    for (int k = 0; k < kmax; ++k) {
        float v[16];
#pragma unroll
        for (int i = 0; i < 16; ++i) {
            int idx = s_idx[pbase + i][k];          // wave-uniform broadcast
            v[i] = fbl[(size_t)idx << 6];
        }
#pragma unroll
        for (int i = 0; i < 16; ++i) {
            acc[i] += s_wgt[pbase + i][k] * v[i];
        }
    }

    // Phase 3: transposed store, one 64B line per lane (4x float4)
    size_t obase = (((size_t)b * CCH + lane) * S + h) * S + (size_t)(w0 + pbase);
    float4* o4 = (float4*)(out + obase);
#pragma unroll
    for (int q = 0; q < 4; ++q) {
        o4[q] = make_float4(acc[4 * q + 0], acc[4 * q + 1],
                            acc[4 * q + 2], acc[4 * q + 3]);
    }
}

extern "C" void kernel_launch(void* const* d_in, const int* in_sizes, int n_in,
                              void* d_out, int out_size, void* d_ws, size_t ws_size,
                              hipStream_t stream) {
    const float* pts  = (const float*)d_in[0];
    const float* feat = (const float*)d_in[1];
    float* out = (float*)d_out;

    unsigned long long* keys = (unsigned long long*)d_ws;
    size_t key_bytes = (size_t)BATCH * S * S * K * sizeof(unsigned long long);
    hipMemsetAsync(keys, 0xFF, key_bytes, stream);   // SENT = all-ones

    int total = BATCH * NPTS * 16;
    scatter_kernel<<<(total + 255) / 256, 256, 0, stream>>>(pts, keys);

    dim3 grid(S / 64, S, BATCH);
    blend_kernel<<<grid, 256, 0, stream>>>(pts, feat, keys, out);
}